// Round 9
// baseline (216.247 us; speedup 1.0000x reference)
//
#include <hip/hip_runtime.h>
#include <hip/hip_bf16.h>
#include <math.h>

// Problem constants (fixed by reference)
#define BATCH 2
#define SEQ 2048
#define DMODEL 1024
#define NHEADS 16
#define DK 64
#define BH (BATCH*NHEADS)   // 32
#define GK 1024             // GEMM K dim (d_model)
#define NX (BATCH*SEQ*DMODEL)   // 4194304
#define NW (DMODEL*DMODEL)      // 1048576

// Inputs/outputs confirmed fp32 (rounds 3-8 passed with this assumption).
// softmax in base-2 with STATIC shift: scores ~ N(0,1); diagonal self-score
// q.q/8 >= 0 guarantees l >= 2^-SHIFT; overflow needs s > ~90 sigma.
#define SCALE2 0.18033688011112042f   // log2(e)/8
#define SHIFT  16.0f

typedef __bf16 bf16_t;
typedef __bf16 bf16x8 __attribute__((ext_vector_type(8)));
typedef __bf16 bf16x4 __attribute__((ext_vector_type(4)));
typedef float  floatx4 __attribute__((ext_vector_type(4)));

// async global->LDS, 16B per lane (m97 pattern; LDS dest must be base+lane*16)
__device__ __forceinline__ void load_lds16(const bf16_t* g, bf16_t* l) {
    __builtin_amdgcn_global_load_lds(
        (const __attribute__((address_space(1))) void*)g,
        (__attribute__((address_space(3))) void*)l,
        16, 0, 0);
}

// ---------------- fp32->bf16 conversion of x,W  +  RoPE tables (fused) ----------------
// grid: 2048 (x) + 2048 (W's) + 256 (tables) = 4352 blocks
__global__ __launch_bounds__(256) void convert_all_kernel(
    const float* __restrict__ x,
    const float* __restrict__ WQ, const float* __restrict__ WK,
    const float* __restrict__ WV, const float* __restrict__ WO,
    const int* __restrict__ pos,
    bf16_t* __restrict__ xb, bf16_t* __restrict__ Wb, float2* __restrict__ csT)
{
    const int blk = blockIdx.x;
    if (blk >= 4096) {                       // RoPE tables: [s][kk] cos/sin
        int idx = (blk - 4096) * 256 + threadIdx.x;   // s*32+kk, 65536 total
        int kk = idx & 31, s = idx >> 5;
        float freq = exp2f((float)kk * (-13.287712379549449f / 32.0f));
        float ang = (float)pos[s] * freq;
        float sn, cs;
        sincosf(ang, &sn, &cs);
        csT[idx] = make_float2(cs, sn);
        return;
    }
    const float* src;
    bf16_t* dst;
    int base;
    if (blk < 2048) {
        src = x; dst = xb; base = blk * 2048;
    } else {
        int wi  = (blk - 2048) >> 9;           // 0..3 : WQ,WK,WV,WO
        base = ((blk - 2048) & 511) * 2048;
        src = (wi == 0) ? WQ : (wi == 1) ? WK : (wi == 2) ? WV : WO;
        dst = Wb + (size_t)wi * NW;
    }
    int i = base + threadIdx.x * 8;
    float4 a = *(const float4*)(src + i);
    float4 b = *(const float4*)(src + i + 4);
    bf16x8 o;
    o[0] = (bf16_t)a.x; o[1] = (bf16_t)a.y; o[2] = (bf16_t)a.z; o[3] = (bf16_t)a.w;
    o[4] = (bf16_t)b.x; o[5] = (bf16_t)b.y; o[6] = (bf16_t)b.z; o[7] = (bf16_t)b.w;
    *(bf16x8*)(dst + i) = o;
}

// ---------------- 128x128 MFMA bf16 GEMM mainloop (C = A * B^T) ----------------
__device__ __forceinline__ void gemm128_mainloop(
    const bf16_t* __restrict__ Arows, const bf16_t* __restrict__ Brows,
    bf16_t (*As)[32], bf16_t (*Bs)[32], int tid, floatx4 acc[4][4], int klen)
{
    const int lane = tid & 63;
    const int w = tid >> 6;
    const int wm = w >> 1, wn = w & 1;
    const int r = lane & 15, q = lane >> 4;

    const int row0 = tid >> 2,         kc0 = (tid & 3) << 3;
    const int row1 = (tid + 256) >> 2, kc1 = kc0;

    for (int kt = 0; kt < klen; kt += 32) {
        __syncthreads();
        load_lds16(Arows + (size_t)row0 * GK + kt + kc0, &As[row0][kc0]);
        load_lds16(Arows + (size_t)row1 * GK + kt + kc1, &As[row1][kc1]);
        load_lds16(Brows + (size_t)row0 * GK + kt + kc0, &Bs[row0][kc0]);
        load_lds16(Brows + (size_t)row1 * GK + kt + kc1, &Bs[row1][kc1]);
        __syncthreads();

        bf16x8 af[4], bfr[4];
        #pragma unroll
        for (int i = 0; i < 4; ++i)
            af[i] = *(const bf16x8*)&As[wm * 64 + i * 16 + r][q << 3];
        #pragma unroll
        for (int j = 0; j < 4; ++j)
            bfr[j] = *(const bf16x8*)&Bs[wn * 64 + j * 16 + r][q << 3];

        #pragma unroll
        for (int i = 0; i < 4; ++i)
            #pragma unroll
            for (int j = 0; j < 4; ++j)
                acc[i][j] = __builtin_amdgcn_mfma_f32_16x16x32_bf16(
                    af[i], bfr[j], acc[i][j], 0, 0, 0);
    }
}

// ---------------- QKV projection + in-register RoPE + coalesced stores ----------------
// grid: (24, 32), block 256
__global__ __launch_bounds__(256) void qkv_gemm_kernel(
    const bf16_t* __restrict__ x, const bf16_t* __restrict__ Wb,
    const float2* __restrict__ csT,
    bf16_t* __restrict__ Qh, bf16_t* __restrict__ Kh, bf16_t* __restrict__ Vt)
{
    __shared__ __align__(16) char qsmem[128 * 136 * 2];   // 34816 B
    bf16_t (*As)[32]  = (bf16_t(*)[32])qsmem;
    bf16_t (*Bs)[32]  = (bf16_t(*)[32])(qsmem + 8192);
    bf16_t (*Tt)[136] = (bf16_t(*)[136])qsmem;            // reused after mainloop

    const int tid = threadIdx.x;
    const int m0 = blockIdx.y * 128;
    const int n0g = blockIdx.x * 128;
    const int which = n0g >> 10;               // 0=Q 1=K 2=V (block-uniform)
    const int nl0 = n0g & 1023;
    const bf16_t* Wsel = Wb + (size_t)which * NW;

    floatx4 acc[4][4];
    #pragma unroll
    for (int i = 0; i < 4; ++i)
        #pragma unroll
        for (int j = 0; j < 4; ++j)
            acc[i][j] = (floatx4){0.f, 0.f, 0.f, 0.f};

    gemm128_mainloop(x + (size_t)m0 * GK, Wsel + (size_t)nl0 * GK, As, Bs, tid, acc, GK);
    __syncthreads();

    const int w = tid >> 6, lane = tid & 63;
    const int wm = w >> 1, wn = w & 1;
    const int r = lane & 15, qd = lane >> 4;

    if (which < 2) {
        #pragma unroll
        for (int i = 0; i < 4; ++i)
            #pragma unroll
            for (int j = 0; j < 4; ++j)
                #pragma unroll
                for (int reg = 0; reg < 4; ++reg)
                    Tt[wm * 64 + i * 16 + qd * 4 + reg][wn * 64 + j * 16 + r] =
                        (bf16_t)acc[i][j][reg];
        __syncthreads();

        bf16_t* dst = (which == 0) ? Qh : Kh;
        #pragma unroll
        for (int k2 = 0; k2 < 8; ++k2) {
            int id = tid + 256 * k2;
            int rowm = id >> 4, ch = id & 15;
            int m = m0 + rowm, b = m >> 11, s = m & 2047;
            int n = nl0 + ch * 8, h = n >> 6, dk = n & 63;
            bf16x8 v = *(const bf16x8*)&Tt[rowm][ch * 8];
            const float4* csp = (const float4*)&csT[(s << 5) + (dk >> 1)];
            float4 c01 = csp[0], c23 = csp[1];
            bf16x8 o;
            float e, od;
            e = (float)v[0]; od = (float)v[1];
            o[0] = (bf16_t)(e * c01.x - od * c01.y); o[1] = (bf16_t)(od * c01.x + e * c01.y);
            e = (float)v[2]; od = (float)v[3];
            o[2] = (bf16_t)(e * c01.z - od * c01.w); o[3] = (bf16_t)(od * c01.z + e * c01.w);
            e = (float)v[4]; od = (float)v[5];
            o[4] = (bf16_t)(e * c23.x - od * c23.y); o[5] = (bf16_t)(od * c23.x + e * c23.y);
            e = (float)v[6]; od = (float)v[7];
            o[6] = (bf16_t)(e * c23.z - od * c23.w); o[7] = (bf16_t)(od * c23.z + e * c23.w);
            *(bf16x8*)(dst + (((size_t)(b << 4) + h) * SEQ + s) * DK + dk) = o;
        }
    } else {
        #pragma unroll
        for (int i = 0; i < 4; ++i)
            #pragma unroll
            for (int j = 0; j < 4; ++j) {
                int n_local = wn * 64 + j * 16 + r;
                int m_base  = wm * 64 + i * 16 + qd * 4;
                bf16x4 t;
                #pragma unroll
                for (int reg = 0; reg < 4; ++reg) t[reg] = (bf16_t)acc[i][j][reg];
                *(bf16x4*)&Tt[n_local][m_base] = t;
            }
        __syncthreads();
        const int b = m0 >> 11, s0 = m0 & 2047;
        #pragma unroll
        for (int k2 = 0; k2 < 8; ++k2) {
            int id = tid + 256 * k2;
            int row = id >> 4, ch = id & 15;
            int n = nl0 + row, h = n >> 6, dk = n & 63;
            bf16x8 val = *(const bf16x8*)&Tt[row][ch * 8];
            *(bf16x8*)(Vt + (((size_t)(b << 4) + h) * DK + dk) * SEQ + s0 + ch * 8) = val;
        }
    }
}

// ---------------- MFMA flash attention: dual q-tiles per wave + split-K ----------------
// 512 threads (8 waves, 2 split-K groups). Each wave owns 16 queries of tile
// hi=31-bx AND 16 of tile lo=bx, processed in ONE K-loop so every bk/bv LDS
// fragment feeds two tile-pairs (LDS reads per MFMA -44%). K/V staged once per
// kb. Static-max softmax. grid: (16, 32)
__global__ __launch_bounds__(512, 4) void attn_mfma_kernel(
    const bf16_t* __restrict__ Qh, const bf16_t* __restrict__ Kh,
    const bf16_t* __restrict__ Vtg, bf16_t* __restrict__ attnO)
{
    __shared__ __align__(16) char smem[73728];
    bf16_t (*Ks)[64][72]    = (bf16_t(*)[64][72])smem;            // [2][64][72]
    bf16_t (*Vs)[64][72]    = (bf16_t(*)[64][72])(smem + 18432);  // [2][64][72]
    bf16_t (*ps)[2][16][72] = (bf16_t(*)[2][16][72])(smem + 36864); // [8][2][16][72]
    float  (*Om)[64][68]    = (float(*)[64][68])smem;             // overlay
    float  (*lsum)[64]      = (float(*)[64])(smem + 36864);       // overlay

    const int tid = threadIdx.x, w = tid >> 6, lane = tid & 63;
    const int grp = w >> 2, wv = w & 3;
    const int r = lane & 15, qd = lane >> 4;
    const int bh = blockIdx.y, bx = blockIdx.x;
    const int qt_hi = 31 - bx, qt_lo = bx;          // qt_hi >= 16 > 15 >= qt_lo
    const int q0h = qt_hi * 64, q0l = qt_lo * 64;
    const int t = tid & 255;
    const int row0 = t >> 3, c80 = (t & 7) * 8;

    const bf16_t* Kbh = Kh  + (size_t)bh * SEQ * DK;
    const bf16_t* Vbh = Vtg + (size_t)bh * DK * SEQ;
    const int b = bh >> 4, h = bh & 15;

    // Q A-fragments for both tiles
    const bf16_t* Qbh = Qh + ((size_t)bh * SEQ + wv * 16 + r) * DK;
    bf16x8 aqh0 = *(const bf16x8*)(Qbh + (size_t)q0h * DK + qd * 8);
    bf16x8 aqh1 = *(const bf16x8*)(Qbh + (size_t)q0h * DK + 32 + qd * 8);
    bf16x8 aql0 = *(const bf16x8*)(Qbh + (size_t)q0l * DK + qd * 8);
    bf16x8 aql1 = *(const bf16x8*)(Qbh + (size_t)q0l * DK + 32 + qd * 8);

    // prefetch this group's first tile (kb = grp <= qt_hi always)
    int j0 = grp * 64;
    bf16x8 pk0 = *(const bf16x8*)(Kbh + (size_t)(j0 + row0) * DK + c80);
    bf16x8 pk1 = *(const bf16x8*)(Kbh + (size_t)(j0 + row0 + 32) * DK + c80);
    bf16x8 pv0 = *(const bf16x8*)(Vbh + (size_t)row0 * SEQ + j0 + c80);
    bf16x8 pv1 = *(const bf16x8*)(Vbh + (size_t)(row0 + 32) * SEQ + j0 + c80);

    floatx4 Oh[4], Ol[4];
    #pragma unroll
    for (int nd = 0; nd < 4; ++nd) {
        Oh[nd] = (floatx4){0.f, 0.f, 0.f, 0.f};
        Ol[nd] = (floatx4){0.f, 0.f, 0.f, 0.f};
    }
    float lh[4] = {0.f, 0.f, 0.f, 0.f}, ll[4] = {0.f, 0.f, 0.f, 0.f};

    const int nIter = (qt_hi >> 1) + 1;
    for (int it = 0; it < nIter; ++it) {
        const int kb = 2 * it + grp;
        const bool act = (kb <= qt_hi);
        const bool lo_act = (kb <= qt_lo);
        __syncthreads();
        if (act) {
            *(bf16x8*)&Ks[grp][row0][c80]      = pk0;
            *(bf16x8*)&Ks[grp][row0 + 32][c80] = pk1;
            *(bf16x8*)&Vs[grp][row0][c80]      = pv0;
            *(bf16x8*)&Vs[grp][row0 + 32][c80] = pv1;
        }
        if (kb + 2 <= qt_hi) {
            const int j0n = (kb + 2) * 64;
            pk0 = *(const bf16x8*)(Kbh + (size_t)(j0n + row0) * DK + c80);
            pk1 = *(const bf16x8*)(Kbh + (size_t)(j0n + row0 + 32) * DK + c80);
            pv0 = *(const bf16x8*)(Vbh + (size_t)row0 * SEQ + j0n + c80);
            pv1 = *(const bf16x8*)(Vbh + (size_t)(row0 + 32) * SEQ + j0n + c80);
        }
        __syncthreads();
        if (!act) continue;

        // ---- QK^T for both tiles, sharing bk fragments ----
        floatx4 ah[4], al[4];
        #pragma unroll
        for (int nt = 0; nt < 4; ++nt) {
            bf16x8 bk0 = *(const bf16x8*)&Ks[grp][nt * 16 + r][qd * 8];
            bf16x8 bk1 = *(const bf16x8*)&Ks[grp][nt * 16 + r][32 + qd * 8];
            floatx4 a = (floatx4){0.f, 0.f, 0.f, 0.f};
            a = __builtin_amdgcn_mfma_f32_16x16x32_bf16(aqh0, bk0, a, 0, 0, 0);
            a = __builtin_amdgcn_mfma_f32_16x16x32_bf16(aqh1, bk1, a, 0, 0, 0);
            ah[nt] = a;
            if (lo_act) {
                floatx4 a2 = (floatx4){0.f, 0.f, 0.f, 0.f};
                a2 = __builtin_amdgcn_mfma_f32_16x16x32_bf16(aql0, bk0, a2, 0, 0, 0);
                a2 = __builtin_amdgcn_mfma_f32_16x16x32_bf16(aql1, bk1, a2, 0, 0, 0);
                al[nt] = a2;
            }
        }

        // ---- softmax + P scatter, hi tile ----
        const bool dh = (kb == qt_hi);
        #pragma unroll
        for (int nt = 0; nt < 4; ++nt)
            #pragma unroll
            for (int rg = 0; rg < 4; ++rg) {
                float s2 = fmaf(ah[nt][rg], SCALE2, -SHIFT);
                if (dh && (nt * 16 + r > wv * 16 + qd * 4 + rg)) s2 = -200.0f;
                float p = exp2f(s2);
                lh[rg] += p;
                ps[w][0][qd * 4 + rg][nt * 16 + r] = (bf16_t)p;
            }
        if (lo_act) {
            const bool dl = (kb == qt_lo);
            #pragma unroll
            for (int nt = 0; nt < 4; ++nt)
                #pragma unroll
                for (int rg = 0; rg < 4; ++rg) {
                    float s2 = fmaf(al[nt][rg], SCALE2, -SHIFT);
                    if (dl && (nt * 16 + r > wv * 16 + qd * 4 + rg)) s2 = -200.0f;
                    float p = exp2f(s2);
                    ll[rg] += p;
                    ps[w][1][qd * 4 + rg][nt * 16 + r] = (bf16_t)p;
                }
        }
        // per-wave DS in-order: writes above complete before these reads
        bf16x8 aph0 = *(const bf16x8*)&ps[w][0][r][qd * 8];
        bf16x8 aph1 = *(const bf16x8*)&ps[w][0][r][32 + qd * 8];
        bf16x8 apl0, apl1;
        if (lo_act) {
            apl0 = *(const bf16x8*)&ps[w][1][r][qd * 8];
            apl1 = *(const bf16x8*)&ps[w][1][r][32 + qd * 8];
        }

        // ---- PV for both tiles, sharing bv fragments ----
        #pragma unroll
        for (int nd = 0; nd < 4; ++nd) {
            bf16x8 bv0 = *(const bf16x8*)&Vs[grp][nd * 16 + r][qd * 8];
            bf16x8 bv1 = *(const bf16x8*)&Vs[grp][nd * 16 + r][32 + qd * 8];
            floatx4 c = Oh[nd];
            c = __builtin_amdgcn_mfma_f32_16x16x32_bf16(aph0, bv0, c, 0, 0, 0);
            c = __builtin_amdgcn_mfma_f32_16x16x32_bf16(aph1, bv1, c, 0, 0, 0);
            Oh[nd] = c;
            if (lo_act) {
                floatx4 c2 = Ol[nd];
                c2 = __builtin_amdgcn_mfma_f32_16x16x32_bf16(apl0, bv0, c2, 0, 0, 0);
                c2 = __builtin_amdgcn_mfma_f32_16x16x32_bf16(apl1, bv1, c2, 0, 0, 0);
                Ol[nd] = c2;
            }
        }
    }

    // ---- epilogue: merge split-K partials through LDS overlay, per tile ----
    #pragma unroll
    for (int tsel = 0; tsel < 2; ++tsel) {
        __syncthreads();   // protect Ks/Vs/ps (or previous Om) before overlay write
        const int q0 = tsel ? q0l : q0h;
        #pragma unroll
        for (int rg = 0; rg < 4; ++rg) {
            float l = tsel ? ll[rg] : lh[rg];
            #pragma unroll
            for (int off = 1; off < 16; off <<= 1) l += __shfl_xor(l, off);
            int rowq = wv * 16 + qd * 4 + rg;
            if (r == 0) lsum[grp][rowq] = l;
            #pragma unroll
            for (int nd = 0; nd < 4; ++nd)
                Om[grp][rowq][nd * 16 + r] = tsel ? Ol[nd][rg] : Oh[nd][rg];
        }
        __syncthreads();
        {
            int rowq = tid >> 3, c8 = (tid & 7) * 8;
            float inv = 1.0f / (lsum[0][rowq] + lsum[1][rowq]);
            float4 a0 = *(const float4*)&Om[0][rowq][c8];
            float4 a1 = *(const float4*)&Om[0][rowq][c8 + 4];
            float4 b0 = *(const float4*)&Om[1][rowq][c8];
            float4 b1 = *(const float4*)&Om[1][rowq][c8 + 4];
            bf16x8 o;
            o[0] = (bf16_t)((a0.x + b0.x) * inv);
            o[1] = (bf16_t)((a0.y + b0.y) * inv);
            o[2] = (bf16_t)((a0.z + b0.z) * inv);
            o[3] = (bf16_t)((a0.w + b0.w) * inv);
            o[4] = (bf16_t)((a1.x + b1.x) * inv);
            o[5] = (bf16_t)((a1.y + b1.y) * inv);
            o[6] = (bf16_t)((a1.z + b1.z) * inv);
            o[7] = (bf16_t)((a1.w + b1.w) * inv);
            int s = q0 + rowq;
            *(bf16x8*)(attnO + ((size_t)b * SEQ + s) * DMODEL + (h << 6) + c8) = o;
        }
    }
}

// ---------------- Output projection, split-K x2 (deterministic) ----------------
// grid: (8, 32, 2), block 256. Each kh-half does K=512 into fp32 partials.
__global__ __launch_bounds__(256) void out_gemm_partial(
    const bf16_t* __restrict__ attnI, const bf16_t* __restrict__ WOb,
    float* __restrict__ P)
{
    __shared__ __align__(16) bf16_t As[128][32];
    __shared__ __align__(16) bf16_t Bs[128][32];

    const int tid = threadIdx.x;
    const int m0 = blockIdx.y * 128;
    const int n0 = blockIdx.x * 128;
    const int kh = blockIdx.z;

    floatx4 acc[4][4];
    #pragma unroll
    for (int i = 0; i < 4; ++i)
        #pragma unroll
        for (int j = 0; j < 4; ++j)
            acc[i][j] = (floatx4){0.f, 0.f, 0.f, 0.f};

    gemm128_mainloop(attnI + (size_t)m0 * GK + kh * 512,
                     WOb + (size_t)n0 * GK + kh * 512, As, Bs, tid, acc, 512);

    float* Pd = P + (size_t)kh * NX;
    const int w = tid >> 6, lane = tid & 63;
    const int wm = w >> 1, wn = w & 1;
    const int r = lane & 15, q = lane >> 4;

    #pragma unroll
    for (int i = 0; i < 4; ++i)
        #pragma unroll
        for (int j = 0; j < 4; ++j)
            #pragma unroll
            for (int reg = 0; reg < 4; ++reg) {
                int m = m0 + wm * 64 + i * 16 + q * 4 + reg;
                int n = n0 + wn * 64 + j * 16 + r;
                Pd[(size_t)m * DMODEL + n] = acc[i][j][reg];
            }
}

// sum the two K-halves -> fp32 output. grid 4096, block 256, float4/thread
__global__ __launch_bounds__(256) void reduce_out_kernel(
    const float* __restrict__ P, float* __restrict__ out)
{
    size_t i = ((size_t)blockIdx.x * 256 + threadIdx.x) * 4;
    float4 a = *(const float4*)(P + i);
    float4 b = *(const float4*)(P + (size_t)NX + i);
    float4 c = make_float4(a.x + b.x, a.y + b.y, a.z + b.z, a.w + b.w);
    *(float4*)(out + i) = c;
}

// ---------------- launch ----------------
extern "C" void kernel_launch(void* const* d_in, const int* in_sizes, int n_in,
                              void* d_out, int out_size, void* d_ws, size_t ws_size,
                              hipStream_t stream)
{
    (void)in_sizes; (void)n_in; (void)out_size; (void)ws_size;

    const float* x  = (const float*)d_in[0];
    const float* WQ = (const float*)d_in[1];
    const float* WK = (const float*)d_in[2];
    const float* WV = (const float*)d_in[3];
    const float* WO = (const float*)d_in[4];
    const int* tpos = (const int*)d_in[5];
    float* out = (float*)d_out;

    // ws: Wb 8MB | csT 0.5MB | attn 8MB | xb 8MB | Qh 8MB | Kh 8MB | Vt 8MB = 48.5MB
    // P (32MB fp32 partials) aliases [xb..Vt] (dead by out-proj time).
    bf16_t* Wb   = (bf16_t*)d_ws;                      // [4][1024][1024]
    float2* csT  = (float2*)(Wb + (size_t)4 * NW);     // [2048][32]
    bf16_t* attn = (bf16_t*)(csT + SEQ * 32);          // [4096][1024]
    bf16_t* xb   = attn + (size_t)NX;                  // [4096][1024]
    bf16_t* Qh   = xb + (size_t)NX;                    // [32][2048][64]
    bf16_t* Kh   = Qh + (size_t)BH * SEQ * DK;
    bf16_t* Vt   = Kh + (size_t)BH * SEQ * DK;         // [32][64][2048]
    float*  P    = (float*)xb;                         // [2][4096][1024] overlay

    convert_all_kernel<<<dim3(4352), dim3(256), 0, stream>>>(
        x, WQ, WK, WV, WO, tpos, xb, Wb, csT);

    qkv_gemm_kernel<<<dim3(3 * DMODEL / 128, BATCH * SEQ / 128), dim3(256), 0, stream>>>(
        xb, Wb, csT, Qh, Kh, Vt);

    attn_mfma_kernel<<<dim3(16, 32), dim3(512), 0, stream>>>(Qh, Kh, Vt, attn);

    out_gemm_partial<<<dim3(DMODEL / 128, BATCH * SEQ / 128, 2), dim3(256), 0, stream>>>(
        attn, Wb + (size_t)3 * NW, P);

    reduce_out_kernel<<<dim3(4096), dim3(256), 0, stream>>>(P, out);
}